// Round 1
// baseline (186.053 us; speedup 1.0000x reference)
//
#include <hip/hip_runtime.h>
#include <hip/hip_bf16.h>

// Problem constants
#define BB 32
#define DD 64
#define HW 1024
#define NN 32768   // BB*HW
#define MM 1024

// ---------------------------------------------------------------------------
// Kernel A: codebook squared norms -> ws[0..1024), zero the loss slot.
// ---------------------------------------------------------------------------
__global__ void k_norms(const float* __restrict__ cb,
                        float* __restrict__ y2,
                        float* __restrict__ loss_slot) {
    int m = blockIdx.x * blockDim.x + threadIdx.x;
    if (m == 0) *loss_slot = 0.0f;
    if (m < MM) {
        const float4* c4 = (const float4*)(cb + (size_t)m * DD);
        float s = 0.f;
#pragma unroll
        for (int k = 0; k < 16; ++k) {
            float4 v = c4[k];
            s += v.x * v.x + v.y * v.y + v.z * v.z + v.w * v.w;
        }
        y2[m] = s;
    }
}

// ---------------------------------------------------------------------------
// Kernel B: fused distance + argmin.
// Block: 512 threads = 8 waves. Block handles 64 consecutive rows n.
// Wave w handles codes [w*128, (w+1)*128) -- wave-uniform codebook access.
// zf[n][d] = z[b*65536 + d*1024 + hw]  (transpose handled by the tile load).
// ---------------------------------------------------------------------------
__global__ __launch_bounds__(512) void k_dist(const float* __restrict__ z,
                                              const float* __restrict__ cb,
                                              const float* __restrict__ y2,
                                              float* __restrict__ dmin_out,
                                              float* __restrict__ ind_out) {
    __shared__ float zt[64][65];       // padded: bank = (r + d) % 32 -> 2-way free
    __shared__ float red_v[8][64];
    __shared__ int   red_ix[8][64];

    const int t    = threadIdx.x;
    const int lane = t & 63;
    const int blk  = blockIdx.x;            // 0..511
    const int b    = blk >> 4;              // 16 blocks per batch
    const int hw0  = (blk & 15) << 6;

    const float* zbase = z + ((size_t)b << 16) + hw0;

    // Stage z tile (coalesced: consecutive threads -> consecutive hw)
    for (int i = t; i < 64 * 64; i += 512) {
        int d = i >> 6, r = i & 63;
        zt[r][d] = zbase[(size_t)d * HW + r];
    }
    __syncthreads();

    // Row into registers + x^2
    float row[64];
    float x2 = 0.f;
#pragma unroll
    for (int d = 0; d < 64; ++d) {
        row[d] = zt[lane][d];
        x2 = __builtin_fmaf(row[d], row[d], x2);
    }

    // Wave-uniform code chunk (readfirstlane to help scalar-load promotion)
    const int wave = __builtin_amdgcn_readfirstlane(t >> 6);   // 0..7
    const int m0   = wave << 7;                                // *128

    const float* cw = cb + ((size_t)m0 << 6);
    float best = 1e30f;
    int   bidx = 0;

    for (int m = 0; m < 128; ++m) {
        const float* c = cw + (m << 6);
        float a0 = 0.f, a1 = 0.f, a2 = 0.f, a3 = 0.f;
#pragma unroll
        for (int d = 0; d < 64; d += 4) {
            a0 = __builtin_fmaf(row[d + 0], c[d + 0], a0);
            a1 = __builtin_fmaf(row[d + 1], c[d + 1], a1);
            a2 = __builtin_fmaf(row[d + 2], c[d + 2], a2);
            a3 = __builtin_fmaf(row[d + 3], c[d + 3], a3);
        }
        float dot = (a0 + a1) + (a2 + a3);
        float partial = y2[m0 + m] - 2.0f * dot;   // x2 added later (argmin-invariant)
        if (partial < best) { best = partial; bidx = m0 + m; }
    }

    red_v[wave][lane]  = best;
    red_ix[wave][lane] = bidx;
    __syncthreads();

    if (t < 64) {
        float bv = red_v[0][t];
        int   bi = red_ix[0][t];
#pragma unroll
        for (int w = 1; w < 8; ++w) {
            float v = red_v[w][t];
            int   ix = red_ix[w][t];
            if (v < bv) { bv = v; bi = ix; }   // strict < : lowest index wins
        }
        int n = (blk << 6) + t;                // n = b*1024 + hw0 + r
        dmin_out[n] = x2 + bv;
        ind_out[n]  = (float)bi;
    }
}

// ---------------------------------------------------------------------------
// Kernel C: q_error, z_q output (transposed layout), loss partial sums.
// Block: 256 threads, handles (b, hw tile of 64) -> same mapping as k_dist.
// noise tile = contiguous 4096 floats; LDS transpose for coalesced output.
// The raw-reshape loss chunks (1024 contiguous z_q elements) fall entirely
// inside one block's tile -> 4 complete s-sums per block, one atomicAdd.
// ---------------------------------------------------------------------------
__global__ __launch_bounds__(256) void k_out(const float* __restrict__ z,
                                             const float* __restrict__ noise,
                                             const float* __restrict__ dmin,
                                             float* __restrict__ zq,
                                             float* __restrict__ loss_slot) {
    __shared__ float nt[64][65];    // nt[d][c] = noise[(n0+c)*64 + d]
    __shared__ float snorm[64];
    __shared__ float scale[64];
    __shared__ float partials[256];
    __shared__ float sq[4];

    const int t   = threadIdx.x;
    const int blk = blockIdx.x;          // 0..511
    const int b   = blk >> 4;
    const int hw0 = (blk & 15) << 6;
    const int n0  = (blk << 6);          // first row of tile

    // Phase 1: load noise tile (fully coalesced float4), transpose into LDS,
    // per-row squared norms via 16-lane shuffle reduction.
    const float4* noise4 = (const float4*)noise;
    const size_t base4 = (size_t)blk * 1024;    // 4096 floats / 4
#pragma unroll
    for (int k = 0; k < 4; ++k) {
        int v = t + 256 * k;                     // float4 index in tile [0,1024)
        float4 vv = noise4[base4 + v];
        int c  = v >> 4;                         // row (hw offset) in tile
        int d0 = (v & 15) << 2;                  // starting d
        nt[d0 + 0][c] = vv.x;
        nt[d0 + 1][c] = vv.y;
        nt[d0 + 2][c] = vv.z;
        nt[d0 + 3][c] = vv.w;
        float p = vv.x * vv.x + vv.y * vv.y + vv.z * vv.z + vv.w * vv.w;
        p += __shfl_xor(p, 1);
        p += __shfl_xor(p, 2);
        p += __shfl_xor(p, 4);
        p += __shfl_xor(p, 8);
        if ((t & 15) == 0) snorm[c] = p;
    }
    __syncthreads();

    // Phase 2: per-row scale = sqrt(max(dmin,0)) / max(||noise||, 1e-9)
    if (t < 64) {
        float dm = dmin[n0 + t];
        float nr = sqrtf(snorm[t]);
        nr = fmaxf(nr, 1e-9f);
        scale[t] = sqrtf(fmaxf(dm, 0.f)) / nr;
    }
    __syncthreads();

    // Phase 3: z_q_out[b,d,hw0+c] = z[...] + nt[d][c]*scale[c]  (coalesced)
    float acc = 0.f;
    const size_t obase = ((size_t)b << 16) + hw0;
#pragma unroll
    for (int it = 0; it < 16; ++it) {
        int flat = it * 256 + t;
        int d = flat >> 6;          // = it*4 + (t>>6), wave-uniform
        int c = t & 63;
        size_t idx = obase + (size_t)d * HW + c;
        float v = z[idx] + nt[d][c] * scale[c];
        zq[idx] = v;
        acc += v;
    }

    // Phase 4: loss. Thread's c is fixed -> belongs to one 16-hw chunk.
    partials[t] = acc;
    __syncthreads();
    if (t < 4) {
        float s = 0.f;
        for (int w = 0; w < 4; ++w)
            for (int j = 0; j < 16; ++j)
                s += partials[w * 64 + t * 16 + j];
        sq[t] = s * s;
    }
    __syncthreads();
    if (t == 0) {
        float contrib = (sq[0] + sq[1] + sq[2] + sq[3]) * (1.0f / 33554432.0f);
        atomicAdd(loss_slot, contrib);
    }
}

// ---------------------------------------------------------------------------
extern "C" void kernel_launch(void* const* d_in, const int* in_sizes, int n_in,
                              void* d_out, int out_size, void* d_ws, size_t ws_size,
                              hipStream_t stream) {
    const float* z        = (const float*)d_in[0];   // (32,64,32,32)
    const float* codebook = (const float*)d_in[1];   // (1024,64)
    const float* noise    = (const float*)d_in[2];   // (32768,64)

    float* out      = (float*)d_out;
    float* zq_out   = out;                 // 2097152 floats
    float* loss_ptr = out + 2097152;       // 1 float
    float* ind_out  = out + 2097153;       // 32768 floats

    float* y2   = (float*)d_ws;            // 1024 floats
    float* dmin = y2 + MM;                 // 32768 floats

    k_norms<<<4, 256, 0, stream>>>(codebook, y2, loss_ptr);
    k_dist<<<512, 512, 0, stream>>>(z, codebook, y2, dmin, ind_out);
    k_out<<<512, 256, 0, stream>>>(z, noise, dmin, zq_out, loss_ptr);
}

// Round 2
// 107.516 us; speedup vs baseline: 1.7305x; 1.7305x over previous
//
#include <hip/hip_runtime.h>
#include <hip/hip_bf16.h>

// Problem constants
#define BB 32
#define DD 64
#define HW 1024
#define NN 32768   // BB*HW
#define MM 1024

typedef _Float16 half8 __attribute__((ext_vector_type(8)));
typedef float    floatx4 __attribute__((ext_vector_type(4)));

#define MFMA16(a, b, c) __builtin_amdgcn_mfma_f32_16x16x32_f16((a), (b), (c), 0, 0, 0)

// lo-term scaling to dodge any fp16-denormal flush in the MFMA pipe
#define LO_SCALE   2048.0f
#define LO_INV     (1.0f / 2048.0f)

// ---------------------------------------------------------------------------
// Kernel A: codebook squared norms -> y2[0..1024), zero the loss slot.
// ---------------------------------------------------------------------------
__global__ void k_norms(const float* __restrict__ cb,
                        float* __restrict__ y2,
                        float* __restrict__ loss_slot) {
    int m = blockIdx.x * blockDim.x + threadIdx.x;
    if (m == 0) *loss_slot = 0.0f;
    if (m < MM) {
        const float4* c4 = (const float4*)(cb + (size_t)m * DD);
        float s = 0.f;
#pragma unroll
        for (int k = 0; k < 16; ++k) {
            float4 v = c4[k];
            s += v.x * v.x + v.y * v.y + v.z * v.z + v.w * v.w;
        }
        y2[m] = s;
    }
}

// ---------------------------------------------------------------------------
// Kernel A2: pre-swizzle -2*codebook into MFMA B-fragment order, fp16 hi/lo.
// B frag for mfma_f32_16x16x32_f16: B[k][n]: n=lane&15, k=(lane>>4)*8+j.
// Storage: ch[((mtile*2+kstep)*64 + lane)*8 + j], same for cl (lo * 2048).
// mtile in [0,64), kstep in {0,1}. Total 8192 half8 = 128KB each.
// ---------------------------------------------------------------------------
__global__ void k_cbprep(const float* __restrict__ cb,
                         _Float16* __restrict__ ch,
                         _Float16* __restrict__ cl) {
    int u = blockIdx.x * blockDim.x + threadIdx.x;   // 0..8191
    if (u >= 64 * 2 * 64) return;
    int lane  = u & 63;
    int kstep = (u >> 6) & 1;
    int mtile = u >> 7;
    int m  = mtile * 16 + (lane & 15);
    int d0 = kstep * 32 + ((lane >> 4) & 3) * 8;
    const float* src = cb + (size_t)m * DD + d0;
    half8 h, l;
#pragma unroll
    for (int j = 0; j < 8; ++j) {
        float x = -2.0f * src[j];
        _Float16 hi = (_Float16)x;
        _Float16 lo = (_Float16)((x - (float)hi) * LO_SCALE);
        h[j] = hi;
        l[j] = lo;
    }
    *(half8*)(ch + (size_t)u * 8) = h;
    *(half8*)(cl + (size_t)u * 8) = l;
}

// ---------------------------------------------------------------------------
// Kernel B: fused distance + argmin via fp16-split MFMA.
// Block: 256 threads = 4 waves, handles 64 rows (4 ntiles of 16).
// Each wave: ALL 4 ntiles x a 16-mtile quarter of the codebook.
// A frags resident in regs (4 ntiles x 2 ksteps x hi/lo = 64 VGPRs).
// B frags streamed from pre-swizzled ws, double-buffered, no in-loop barrier.
// acc1 = y2[col] + sum hi*hi ; acc2 = 2048*(hi*lo + lo*hi); v = acc1 + acc2/2048.
// dist_partial = y2 - 2*dot (x2 added at epilogue, argmin-invariant).
// ---------------------------------------------------------------------------
__global__ __launch_bounds__(256, 2) void k_dist(const float* __restrict__ z,
                                                 const _Float16* __restrict__ ch,
                                                 const _Float16* __restrict__ cl,
                                                 const float* __restrict__ y2,
                                                 float* __restrict__ dmin_out,
                                                 float* __restrict__ ind_out) {
    __shared__ float zt[64][65];
    __shared__ float y2s[MM];
    __shared__ float x2p[64][4];
    __shared__ float x2s[64];
    __shared__ float bestv_s[4][64];
    __shared__ int   besti_s[4][64];

    const int t    = threadIdx.x;
    const int lane = t & 63;
    const int wv   = t >> 6;            // wave 0..3
    const int quad = lane >> 4;         // 0..3
    const int col  = lane & 15;         // 0..15
    const int blk  = blockIdx.x;        // 0..511
    const int b    = blk >> 4;
    const int hw0  = (blk & 15) << 6;

    const float* zbase = z + ((size_t)b << 16) + hw0;

    // ---- stage z tile (coalesced) + y2 ----
    for (int i = t; i < 64 * 64; i += 256) {
        int d = i >> 6, r = i & 63;
        zt[r][d] = zbase[(size_t)d * HW + r];
    }
    for (int i = t; i < MM; i += 256) y2s[i] = y2[i];
    __syncthreads();

    // ---- x2 partials + build resident A fragments (hi/lo fp16) ----
    {
        int row = t & 63, seg = t >> 6;
        float s = 0.f;
#pragma unroll
        for (int j = 0; j < 16; ++j) {
            float v = zt[row][seg * 16 + j];
            s = __builtin_fmaf(v, v, s);
        }
        x2p[row][seg] = s;
    }

    // A frag: A[m][k]: m=lane&15 (row within ntile), k=(lane>>4)*8+j
    half8 ah[4][2], al[4][2];
#pragma unroll
    for (int nt = 0; nt < 4; ++nt) {
        int row = nt * 16 + col;
#pragma unroll
        for (int ks = 0; ks < 2; ++ks) {
            int d0 = ks * 32 + quad * 8;
            half8 h, l;
#pragma unroll
            for (int j = 0; j < 8; ++j) {
                float x = zt[row][d0 + j];
                _Float16 hi = (_Float16)x;
                _Float16 lo = (_Float16)((x - (float)hi) * LO_SCALE);
                h[j] = hi;
                l[j] = lo;
            }
            ah[nt][ks] = h;
            al[nt][ks] = l;
        }
    }
    __syncthreads();
    if (t < 64) x2s[t] = x2p[t][0] + x2p[t][1] + x2p[t][2] + x2p[t][3];

    // ---- main loop: 16 mtiles per wave, double-buffered B frags ----
    const half8* ch8 = (const half8*)ch;
    const half8* cl8 = (const half8*)cl;

    float best[16];
    int   bmt[16];
#pragma unroll
    for (int s = 0; s < 16; ++s) { best[s] = 1e30f; bmt[s] = 0; }

    const int mt0 = wv * 16;
    half8 bh0 = ch8[((mt0 * 2 + 0) << 6) + lane];
    half8 bl0 = cl8[((mt0 * 2 + 0) << 6) + lane];
    half8 bh1 = ch8[((mt0 * 2 + 1) << 6) + lane];
    half8 bl1 = cl8[((mt0 * 2 + 1) << 6) + lane];

#pragma unroll 2
    for (int i = 0; i < 16; ++i) {
        const int mt  = mt0 + i;
        const int mtn = mt + (i < 15 ? 1 : 0);
        half8 nh0 = ch8[((mtn * 2 + 0) << 6) + lane];
        half8 nl0 = cl8[((mtn * 2 + 0) << 6) + lane];
        half8 nh1 = ch8[((mtn * 2 + 1) << 6) + lane];
        half8 nl1 = cl8[((mtn * 2 + 1) << 6) + lane];

        float y2v = y2s[(mt << 4) + col];
        floatx4 a1[4], a2[4];
#pragma unroll
        for (int nt = 0; nt < 4; ++nt) {
            floatx4 i1 = {y2v, y2v, y2v, y2v};
            floatx4 i2 = {0.f, 0.f, 0.f, 0.f};
            a1[nt] = i1;
            a2[nt] = i2;
        }
#pragma unroll
        for (int nt = 0; nt < 4; ++nt) {
            a1[nt] = MFMA16(ah[nt][0], bh0, a1[nt]);   // hi*hi (k 0..31)
            a2[nt] = MFMA16(al[nt][0], bh0, a2[nt]);   // lo*hi
            a2[nt] = MFMA16(ah[nt][0], bl0, a2[nt]);   // hi*lo
            a1[nt] = MFMA16(ah[nt][1], bh1, a1[nt]);   // hi*hi (k 32..63)
            a2[nt] = MFMA16(al[nt][1], bh1, a2[nt]);
            a2[nt] = MFMA16(ah[nt][1], bl1, a2[nt]);
        }
#pragma unroll
        for (int nt = 0; nt < 4; ++nt) {
#pragma unroll
            for (int r = 0; r < 4; ++r) {
                float v = __builtin_fmaf(a2[nt][r], LO_INV, a1[nt][r]);
                int s = nt * 4 + r;
                bool c = v < best[s];
                best[s] = c ? v : best[s];
                bmt[s]  = c ? mt : bmt[s];
            }
        }
        bh0 = nh0; bl0 = nl0; bh1 = nh1; bl1 = nl1;
    }

    // ---- per-wave cross-lane argmin (16 lanes share a row), then LDS ----
#pragma unroll
    for (int nt = 0; nt < 4; ++nt) {
#pragma unroll
        for (int r = 0; r < 4; ++r) {
            int s = nt * 4 + r;
            float v  = best[s];
            int  idx = bmt[s] * 16 + col;
#pragma unroll
            for (int mask = 1; mask <= 8; mask <<= 1) {
                float v2 = __shfl_xor(v, mask);
                int   i2 = __shfl_xor(idx, mask);
                if (v2 < v || (v2 == v && i2 < idx)) { v = v2; idx = i2; }
            }
            if (col == 0) {
                int rl = nt * 16 + quad * 4 + r;
                bestv_s[wv][rl] = v;
                besti_s[wv][rl] = idx;
            }
        }
    }
    __syncthreads();

    // ---- merge the 4 waves' code-quarters, write outputs ----
    if (t < 64) {
        float bv = bestv_s[0][t];
        int   bi = besti_s[0][t];
#pragma unroll
        for (int w = 1; w < 4; ++w) {
            float v = bestv_s[w][t];
            int   ix = besti_s[w][t];
            if (v < bv || (v == bv && ix < bi)) { bv = v; bi = ix; }
        }
        int n = (blk << 6) + t;
        dmin_out[n] = x2s[t] + bv;
        ind_out[n]  = (float)bi;
    }
}

// ---------------------------------------------------------------------------
// Kernel C: q_error, z_q output (transposed layout), loss partial sums.
// (unchanged from the passing round-1 kernel)
// ---------------------------------------------------------------------------
__global__ __launch_bounds__(256) void k_out(const float* __restrict__ z,
                                             const float* __restrict__ noise,
                                             const float* __restrict__ dmin,
                                             float* __restrict__ zq,
                                             float* __restrict__ loss_slot) {
    __shared__ float nt[64][65];    // nt[d][c] = noise[(n0+c)*64 + d]
    __shared__ float snorm[64];
    __shared__ float scale[64];
    __shared__ float partials[256];
    __shared__ float sq[4];

    const int t   = threadIdx.x;
    const int blk = blockIdx.x;          // 0..511
    const int b   = blk >> 4;
    const int hw0 = (blk & 15) << 6;
    const int n0  = (blk << 6);          // first row of tile

    const float4* noise4 = (const float4*)noise;
    const size_t base4 = (size_t)blk * 1024;    // 4096 floats / 4
#pragma unroll
    for (int k = 0; k < 4; ++k) {
        int v = t + 256 * k;                     // float4 index in tile [0,1024)
        float4 vv = noise4[base4 + v];
        int c  = v >> 4;                         // row (hw offset) in tile
        int d0 = (v & 15) << 2;                  // starting d
        nt[d0 + 0][c] = vv.x;
        nt[d0 + 1][c] = vv.y;
        nt[d0 + 2][c] = vv.z;
        nt[d0 + 3][c] = vv.w;
        float p = vv.x * vv.x + vv.y * vv.y + vv.z * vv.z + vv.w * vv.w;
        p += __shfl_xor(p, 1);
        p += __shfl_xor(p, 2);
        p += __shfl_xor(p, 4);
        p += __shfl_xor(p, 8);
        if ((t & 15) == 0) snorm[c] = p;
    }
    __syncthreads();

    if (t < 64) {
        float dm = dmin[n0 + t];
        float nr = sqrtf(snorm[t]);
        nr = fmaxf(nr, 1e-9f);
        scale[t] = sqrtf(fmaxf(dm, 0.f)) / nr;
    }
    __syncthreads();

    float acc = 0.f;
    const size_t obase = ((size_t)b << 16) + hw0;
#pragma unroll
    for (int it = 0; it < 16; ++it) {
        int flat = it * 256 + t;
        int d = flat >> 6;
        int c = t & 63;
        size_t idx = obase + (size_t)d * HW + c;
        float v = z[idx] + nt[d][c] * scale[c];
        zq[idx] = v;
        acc += v;
    }

    partials[t] = acc;
    __syncthreads();
    if (t < 4) {
        float s = 0.f;
        for (int w = 0; w < 4; ++w)
            for (int j = 0; j < 16; ++j)
                s += partials[w * 64 + t * 16 + j];
        sq[t] = s * s;
    }
    __syncthreads();
    if (t == 0) {
        float contrib = (sq[0] + sq[1] + sq[2] + sq[3]) * (1.0f / 33554432.0f);
        atomicAdd(loss_slot, contrib);
    }
}

// ---------------------------------------------------------------------------
extern "C" void kernel_launch(void* const* d_in, const int* in_sizes, int n_in,
                              void* d_out, int out_size, void* d_ws, size_t ws_size,
                              hipStream_t stream) {
    const float* z        = (const float*)d_in[0];   // (32,64,32,32)
    const float* codebook = (const float*)d_in[1];   // (1024,64)
    const float* noise    = (const float*)d_in[2];   // (32768,64)

    float* out      = (float*)d_out;
    float* zq_out   = out;                 // 2097152 floats
    float* loss_ptr = out + 2097152;       // 1 float
    float* ind_out  = out + 2097153;       // 32768 floats

    float* y2       = (float*)d_ws;        // 1024 floats
    float* dmin     = y2 + MM;             // 32768 floats
    _Float16* ch    = (_Float16*)(dmin + NN);   // 65536 halves (128KB)
    _Float16* cl    = ch + 65536;               // 65536 halves (128KB)

    k_norms <<<4,  256, 0, stream>>>(codebook, y2, loss_ptr);
    k_cbprep<<<32, 256, 0, stream>>>(codebook, ch, cl);
    k_dist  <<<512, 256, 0, stream>>>(z, ch, cl, y2, dmin, ind_out);
    k_out   <<<512, 256, 0, stream>>>(z, noise, dmin, zq_out, loss_ptr);
}

// Round 3
// 98.715 us; speedup vs baseline: 1.8847x; 1.0891x over previous
//
#include <hip/hip_runtime.h>
#include <hip/hip_bf16.h>

// Problem constants
#define BB 32
#define DD 64
#define HW 1024
#define NN 32768   // BB*HW
#define MM 1024

typedef _Float16 half8 __attribute__((ext_vector_type(8)));
typedef float    floatx4 __attribute__((ext_vector_type(4)));

#define MFMA16(a, b, c) __builtin_amdgcn_mfma_f32_16x16x32_f16((a), (b), (c), 0, 0, 0)

// lo-term scaling to dodge fp16-denormal flush in the MFMA pipe
#define LO_SCALE   2048.0f
#define LO_INV     (1.0f / 2048.0f)

// ---------------------------------------------------------------------------
// Kernel 1 (prep): swizzle -2*codebook into MFMA B-frag order (fp16 hi/lo),
// compute codebook squared norms, zero the loss slot.  16 blocks x 512.
// B frag for mfma_f32_16x16x32_f16: B[k][n]: n=lane&15, k=(lane>>4)*8+j.
// Storage: ch[((mtile*2+kstep)*64 + lane)*8 + j]; cl = lo * 2048.
// ---------------------------------------------------------------------------
__global__ void k_prep(const float* __restrict__ cb,
                       _Float16* __restrict__ ch,
                       _Float16* __restrict__ cl,
                       float* __restrict__ y2,
                       float* __restrict__ loss_slot) {
    int u = blockIdx.x * blockDim.x + threadIdx.x;   // 0..8191
    if (u == 0) *loss_slot = 0.0f;

    if (u < 64 * 2 * 64) {
        int lane  = u & 63;
        int kstep = (u >> 6) & 1;
        int mtile = u >> 7;
        int m  = mtile * 16 + (lane & 15);
        int d0 = kstep * 32 + ((lane >> 4) & 3) * 8;
        const float* src = cb + (size_t)m * DD + d0;
        half8 h, l;
#pragma unroll
        for (int j = 0; j < 8; ++j) {
            float x = -2.0f * src[j];
            _Float16 hi = (_Float16)x;
            _Float16 lo = (_Float16)((x - (float)hi) * LO_SCALE);
            h[j] = hi;
            l[j] = lo;
        }
        *(half8*)(ch + (size_t)u * 8) = h;
        *(half8*)(cl + (size_t)u * 8) = l;
    }

    if (u < MM) {
        const float4* c4 = (const float4*)(cb + (size_t)u * DD);
        float s = 0.f;
#pragma unroll
        for (int k = 0; k < 16; ++k) {
            float4 v = c4[k];
            s += v.x * v.x + v.y * v.y + v.z * v.z + v.w * v.w;
        }
        y2[u] = s;
    }
}

// ---------------------------------------------------------------------------
// Kernel 2 (main): fused distance + argmin + q_error + z_q + loss.
// 512 blocks x 512 threads (8 waves).  Block = 64 rows (b = blk>>4,
// hw0 = (blk&15)<<6).  Wave w: row-half nthalf = w&1 (32 rows = 2 ntiles),
// code-quarter cq = w>>1 (16 mtiles = 256 codes).
// A frags resident (32 VGPRs); B frags streamed from pre-swizzled ws,
// double-buffered.  acc1 = y2 + hi*hi ; acc2 = 2048*(hi*lo+lo*hi);
// dist_partial = acc1 + acc2/2048 (x2 added at epilogue, argmin-invariant).
// Noise tile prefetched into LDS before the MFMA loop; epilogue computes
// scale in LDS (no dmin global round-trip) and writes z_q + loss.
// ---------------------------------------------------------------------------
__global__ __launch_bounds__(512, 4) void k_main(const float* __restrict__ z,
                                                 const float* __restrict__ noise,
                                                 const _Float16* __restrict__ ch,
                                                 const _Float16* __restrict__ cl,
                                                 const float* __restrict__ y2,
                                                 float* __restrict__ zq,
                                                 float* __restrict__ ind_out,
                                                 float* __restrict__ loss_slot) {
    __shared__ float zt[64][65];     // zt[row(hw)][d]
    __shared__ float nt[64][65];     // nt[d][row(hw)]
    __shared__ float y2s[MM];
    __shared__ float x2p[64][8];
    __shared__ float snorm[64];
    __shared__ float scale_s[64];
    __shared__ float bestv_s[4][64]; // [code-quarter][row]
    __shared__ int   besti_s[4][64];
    __shared__ float partials[512];
    __shared__ float sq[4];

    const int t    = threadIdx.x;
    const int lane = t & 63;
    const int wv   = t >> 6;            // wave 0..7
    const int nth  = wv & 1;            // row half
    const int cq   = wv >> 1;           // code quarter
    const int quad = lane >> 4;         // 0..3
    const int col  = lane & 15;         // 0..15
    const int blk  = blockIdx.x;        // 0..511
    const int b    = blk >> 4;
    const int hw0  = (blk & 15) << 6;

    const float* zbase = z + ((size_t)b << 16) + hw0;

    // ---- stage z tile (coalesced), y2, noise tile (+ row norms) ----
    for (int i = t; i < 64 * 64; i += 512) {
        int d = i >> 6, r = i & 63;
        zt[r][d] = zbase[(size_t)d * HW + r];
    }
    for (int i = t; i < MM; i += 512) y2s[i] = y2[i];

    {
        const float4* noise4 = (const float4*)noise;
        const size_t base4 = (size_t)blk * 1024;     // 4096 floats / 4
#pragma unroll
        for (int k = 0; k < 2; ++k) {
            int v = t + 512 * k;                     // float4 index [0,1024)
            float4 vv = noise4[base4 + v];
            int c  = v >> 4;
            int d0 = (v & 15) << 2;
            nt[d0 + 0][c] = vv.x;
            nt[d0 + 1][c] = vv.y;
            nt[d0 + 2][c] = vv.z;
            nt[d0 + 3][c] = vv.w;
            float p = vv.x * vv.x + vv.y * vv.y + vv.z * vv.z + vv.w * vv.w;
            p += __shfl_xor(p, 1);
            p += __shfl_xor(p, 2);
            p += __shfl_xor(p, 4);
            p += __shfl_xor(p, 8);
            if ((t & 15) == 0) snorm[c] = p;
        }
    }
    __syncthreads();

    // ---- x2 partials + resident A fragments (hi/lo fp16) ----
    {
        int row = t & 63, seg = t >> 6;
        float s = 0.f;
#pragma unroll
        for (int j = 0; j < 8; ++j) {
            float v = zt[row][seg * 8 + j];
            s = __builtin_fmaf(v, v, s);
        }
        x2p[row][seg] = s;
    }

    // A frag: A[m][k]: m=lane&15, k=(lane>>4)*8+j.  nt2 tiles of 16 rows.
    half8 ah[2][2], al[2][2];
#pragma unroll
    for (int nt2 = 0; nt2 < 2; ++nt2) {
        int row = nth * 32 + nt2 * 16 + col;
#pragma unroll
        for (int ks = 0; ks < 2; ++ks) {
            int d0 = ks * 32 + quad * 8;
            half8 h, l;
#pragma unroll
            for (int j = 0; j < 8; ++j) {
                float x = zt[row][d0 + j];
                _Float16 hi = (_Float16)x;
                _Float16 lo = (_Float16)((x - (float)hi) * LO_SCALE);
                h[j] = hi;
                l[j] = lo;
            }
            ah[nt2][ks] = h;
            al[nt2][ks] = l;
        }
    }
    __syncthreads();

    // ---- main loop: 16 mtiles per wave, double-buffered B frags ----
    const half8* ch8 = (const half8*)ch;
    const half8* cl8 = (const half8*)cl;

    float best[8];
    int   bmt[8];
#pragma unroll
    for (int s = 0; s < 8; ++s) { best[s] = 1e30f; bmt[s] = 0; }

    const int mt0 = cq * 16;
    half8 bh0 = ch8[((mt0 * 2 + 0) << 6) + lane];
    half8 bl0 = cl8[((mt0 * 2 + 0) << 6) + lane];
    half8 bh1 = ch8[((mt0 * 2 + 1) << 6) + lane];
    half8 bl1 = cl8[((mt0 * 2 + 1) << 6) + lane];

#pragma unroll 2
    for (int i = 0; i < 16; ++i) {
        const int mt  = mt0 + i;
        const int mtn = mt + (i < 15 ? 1 : 0);
        half8 nh0 = ch8[((mtn * 2 + 0) << 6) + lane];
        half8 nl0 = cl8[((mtn * 2 + 0) << 6) + lane];
        half8 nh1 = ch8[((mtn * 2 + 1) << 6) + lane];
        half8 nl1 = cl8[((mtn * 2 + 1) << 6) + lane];

        float y2v = y2s[(mt << 4) + col];
        floatx4 a1[2], a2[2];
#pragma unroll
        for (int n2 = 0; n2 < 2; ++n2) {
            floatx4 i1 = {y2v, y2v, y2v, y2v};
            floatx4 i2 = {0.f, 0.f, 0.f, 0.f};
            a1[n2] = i1;
            a2[n2] = i2;
        }
#pragma unroll
        for (int n2 = 0; n2 < 2; ++n2) {
            a1[n2] = MFMA16(ah[n2][0], bh0, a1[n2]);   // hi*hi (k 0..31)
            a2[n2] = MFMA16(al[n2][0], bh0, a2[n2]);   // lo*hi
            a2[n2] = MFMA16(ah[n2][0], bl0, a2[n2]);   // hi*lo
            a1[n2] = MFMA16(ah[n2][1], bh1, a1[n2]);   // hi*hi (k 32..63)
            a2[n2] = MFMA16(al[n2][1], bh1, a2[n2]);
            a2[n2] = MFMA16(ah[n2][1], bl1, a2[n2]);
        }
#pragma unroll
        for (int n2 = 0; n2 < 2; ++n2) {
#pragma unroll
            for (int r = 0; r < 4; ++r) {
                float v = __builtin_fmaf(a2[n2][r], LO_INV, a1[n2][r]);
                int s = n2 * 4 + r;
                bool c = v < best[s];
                best[s] = c ? v : best[s];
                bmt[s]  = c ? mt : bmt[s];
            }
        }
        bh0 = nh0; bl0 = nl0; bh1 = nh1; bl1 = nl1;
    }

    // ---- per-wave cross-lane argmin (16 lanes share a row), then LDS ----
#pragma unroll
    for (int n2 = 0; n2 < 2; ++n2) {
#pragma unroll
        for (int r = 0; r < 4; ++r) {
            int s = n2 * 4 + r;
            float v  = best[s];
            int  idx = bmt[s] * 16 + col;
#pragma unroll
            for (int mask = 1; mask <= 8; mask <<= 1) {
                float v2 = __shfl_xor(v, mask);
                int   i2 = __shfl_xor(idx, mask);
                if (v2 < v || (v2 == v && i2 < idx)) { v = v2; idx = i2; }
            }
            if (col == 0) {
                int rl = nth * 32 + n2 * 16 + quad * 4 + r;
                bestv_s[cq][rl] = v;
                besti_s[cq][rl] = idx;
            }
        }
    }
    __syncthreads();

    // ---- merge code-quarters; write ind; compute scale in LDS ----
    if (t < 64) {
        float bv = bestv_s[0][t];
        int   bi = besti_s[0][t];
#pragma unroll
        for (int w = 1; w < 4; ++w) {
            float v = bestv_s[w][t];
            int   ix = besti_s[w][t];
            if (v < bv || (v == bv && ix < bi)) { bv = v; bi = ix; }
        }
        float x2 = 0.f;
#pragma unroll
        for (int s = 0; s < 8; ++s) x2 += x2p[t][s];
        float dm = x2 + bv;
        int n = (blk << 6) + t;
        ind_out[n] = (float)bi;
        float nr = fmaxf(sqrtf(snorm[t]), 1e-9f);
        scale_s[t] = sqrtf(fmaxf(dm, 0.f)) / nr;
    }
    __syncthreads();

    // ---- z_q write (coalesced, z from LDS) + loss partials ----
    float acc = 0.f;
    const size_t obase = ((size_t)b << 16) + hw0;
#pragma unroll
    for (int it = 0; it < 8; ++it) {
        int flat = it * 512 + t;
        int d = flat >> 6;               // wave-uniform
        int c = t & 63;
        float v = zt[c][d] + nt[d][c] * scale_s[c];
        zq[obase + (size_t)d * HW + c] = v;
        acc += v;
    }

    partials[t] = acc;
    __syncthreads();
    if (t < 4) {
        float s = 0.f;
        for (int g = 0; g < 8; ++g)
            for (int j = 0; j < 16; ++j)
                s += partials[g * 64 + t * 16 + j];
        sq[t] = s * s;
    }
    __syncthreads();
    if (t == 0) {
        float contrib = (sq[0] + sq[1] + sq[2] + sq[3]) * (1.0f / 33554432.0f);
        atomicAdd(loss_slot, contrib);
    }
}

// ---------------------------------------------------------------------------
extern "C" void kernel_launch(void* const* d_in, const int* in_sizes, int n_in,
                              void* d_out, int out_size, void* d_ws, size_t ws_size,
                              hipStream_t stream) {
    const float* z        = (const float*)d_in[0];   // (32,64,32,32)
    const float* codebook = (const float*)d_in[1];   // (1024,64)
    const float* noise    = (const float*)d_in[2];   // (32768,64)

    float* out      = (float*)d_out;
    float* zq_out   = out;                 // 2097152 floats
    float* loss_ptr = out + 2097152;       // 1 float
    float* ind_out  = out + 2097153;       // 32768 floats

    float* y2       = (float*)d_ws;             // 1024 floats
    _Float16* ch    = (_Float16*)(y2 + MM);     // 65536 halves (128KB)
    _Float16* cl    = ch + 65536;               // 65536 halves (128KB)

    k_prep<<<16,  512, 0, stream>>>(codebook, ch, cl, y2, loss_ptr);
    k_main<<<512, 512, 0, stream>>>(z, noise, ch, cl, y2,
                                    zq_out, ind_out, loss_ptr);
}